// Round 5
// baseline (674.905 us; speedup 1.0000x reference)
//
#include <hip/hip_runtime.h>

// Problem constants
#define N_ROWS   32768      // 64*512 flattened z rows
#define KCODES   1024
#define DDIM     256
#define RPB      48         // rows per argmin block (As=48KB -> 3 blocks/CU)
#define NBLK     683        // ceil(32768/48)

// d_out float offsets (outputs concatenated in reference return order)
#define O_ZQ     0                    // 8388608
#define O_LOSS   8388608              // 1
#define O_IDX    8388609              // 32768
#define O_NCS    8421377              // 1024
#define O_NEA    8422401              // 262144
#define O_NEMB   8684545              // 262144

// workspace float offsets
#define W_ESUM   0                    // 262144
#define W_ENORM  262144               // 1024
#define W_LOSSP  263168               // 1024 (683 used)
#define W_CNT    264192               // 1024 ints (memset to 0)
#define W_OFF    265216               // 1024 ints
#define W_CUR    266240               // 1024 ints
#define W_N      267264               // 1
#define W_IDX    267776               // 32768 ints
#define W_SORT   300544               // 32768 ints
// total 333312 floats ~= 1.27 MB

typedef _Float16 half_t;
typedef __attribute__((ext_vector_type(8))) _Float16 half8;
typedef __attribute__((ext_vector_type(4))) _Float16 half4v;
typedef __attribute__((ext_vector_type(4))) float floatx4;

// ---------------------------------------------------------------------------
// ||e_k||^2 + split emb into fp16 hi/lo. 1024 blocks x 64 threads.
__global__ __launch_bounds__(64)
void k_prep(const float* __restrict__ emb, float* __restrict__ enorm,
            half_t* __restrict__ ehi, half_t* __restrict__ elo) {
    int c = blockIdx.x;
    int t = threadIdx.x;
    float4 v = *(const float4*)(emb + c * DDIM + t * 4);
    half4v hi, lo;
    hi[0] = (half_t)v.x; lo[0] = (half_t)(v.x - (float)hi[0]);
    hi[1] = (half_t)v.y; lo[1] = (half_t)(v.y - (float)hi[1]);
    hi[2] = (half_t)v.z; lo[2] = (half_t)(v.z - (float)hi[2]);
    hi[3] = (half_t)v.w; lo[3] = (half_t)(v.w - (float)hi[3]);
    *(half4v*)(ehi + c * DDIM + t * 4) = hi;
    *(half4v*)(elo + c * DDIM + t * 4) = lo;
    float s = v.x * v.x + v.y * v.y + v.z * v.z + v.w * v.w;
    #pragma unroll
    for (int off = 32; off > 0; off >>= 1) s += __shfl_down(s, off);
    if (t == 0) enorm[c] = s;
}

// ---------------------------------------------------------------------------
// MFMA argmin: barrier-free K-loop, depth-2 B prefetch, fused z_q epilogue +
// count histogram. 48-row blocks: LDS 48KB -> 3 blocks/CU; launch_bounds
// (256,3) caps VGPR at ~170 -> 12 waves/CU (round-4 was 8: VGPR=256 + 64KB).
__global__ __launch_bounds__(256, 3)
void k_argmin(const float* __restrict__ z, const half_t* __restrict__ ehi,
              const half_t* __restrict__ elo, const float* __restrict__ enorm,
              const float* __restrict__ embf,
              int* __restrict__ out_idx, float* __restrict__ out_idx_f,
              float* __restrict__ out_zq, float* __restrict__ lossp,
              int* __restrict__ counts_i) {
    __shared__ __align__(16) half_t As[RPB * 512];   // 48 KB

    const int tid  = threadIdx.x;
    const int w    = tid >> 6;
    const int lane = tid & 63;
    const int tx   = lane & 15;
    const int quad = lane >> 4;
    const int rbase = blockIdx.x * RPB;

    // ---- stage A: read z fp32 (row-clamped), split hi/lo, swizzled LDS store
    #pragma unroll
    for (int it = 0; it < 6; ++it) {
        int f   = tid + it * 256;
        int row = f >> 5;             // 0..47
        int g   = f & 31;
        int grow = rbase + row; if (grow > N_ROWS - 1) grow = N_ROWS - 1;
        const float* zp = z + (size_t)grow * DDIM + g * 8;
        float4 v0 = *(const float4*)zp;
        float4 v1 = *(const float4*)(zp + 4);
        half8 hi, lo;
        hi[0] = (half_t)v0.x; lo[0] = (half_t)(v0.x - (float)hi[0]);
        hi[1] = (half_t)v0.y; lo[1] = (half_t)(v0.y - (float)hi[1]);
        hi[2] = (half_t)v0.z; lo[2] = (half_t)(v0.z - (float)hi[2]);
        hi[3] = (half_t)v0.w; lo[3] = (half_t)(v0.w - (float)hi[3]);
        hi[4] = (half_t)v1.x; lo[4] = (half_t)(v1.x - (float)hi[4]);
        hi[5] = (half_t)v1.y; lo[5] = (half_t)(v1.y - (float)hi[5]);
        hi[6] = (half_t)v1.z; lo[6] = (half_t)(v1.z - (float)hi[6]);
        hi[7] = (half_t)v1.w; lo[7] = (half_t)(v1.w - (float)hi[7]);
        int sw = row & 7;
        *(half8*)(&As[row * 512 + ((g ^ sw)) * 8])        = hi;  // k8 = g
        *(half8*)(&As[row * 512 + (((32 + g) ^ sw)) * 8]) = lo;  // k8 = 32+g
    }
    __syncthreads();                  // the ONLY main-loop barrier

    floatx4 zero4 = {0.f, 0.f, 0.f, 0.f};
    float bd[3][4];
    int   bi[3][4];
    #pragma unroll
    for (int mt = 0; mt < 3; ++mt)
        #pragma unroll
        for (int r = 0; r < 4; ++r) { bd[mt][r] = 3.402823466e38f; bi[mt][r] = 0; }

    for (int g4 = 0; g4 < 4; ++g4) {
        const int cb = w * 256 + g4 * 64;
        floatx4 acc[3][4];
        #pragma unroll
        for (int mt = 0; mt < 3; ++mt)
            #pragma unroll
            for (int ns = 0; ns < 4; ++ns) acc[mt][ns] = zero4;

        size_t crow[4];
        #pragma unroll
        for (int ns = 0; ns < 4; ++ns)
            crow[ns] = (size_t)(cb + ns * 16 + tx) * DDIM + quad * 8;

        // depth-2 rolling B prefetch: seg c = ks>>3 (0:hi.hi 1:hi.lo 2:lo.hi)
        half8 B0[4], B1[4], B2[4];
        #define LOADB(P, BUF)                                                  \
            {   const half_t* srcp = (((P) >> 3) == 1) ? elo : ehi;            \
                const int koffp = ((P) & 7) * 32;                              \
                _Pragma("unroll")                                              \
                for (int ns = 0; ns < 4; ++ns)                                 \
                    BUF[ns] = *(const half8*)(srcp + crow[ns] + koffp); }
        LOADB(0, B0);
        LOADB(1, B1);

        #pragma unroll
        for (int ks = 0; ks < 24; ++ks) {
            if (ks + 2 < 24) {
                if ((ks % 3) == 0)      { LOADB(ks + 2, B2); }
                else if ((ks % 3) == 1) { LOADB(ks + 2, B0); }
                else                    { LOADB(ks + 2, B1); }
            }
            const int c   = ks >> 3;
            const int k8b = (c == 2 ? 32 : 0) + (ks & 7) * 4;
            half8 a[3];
            #pragma unroll
            for (int mt = 0; mt < 3; ++mt) {
                int row = mt * 16 + tx;
                a[mt] = *(half8*)(&As[row * 512 + ((k8b + quad) ^ (row & 7)) * 8]);
            }
            #pragma unroll
            for (int mt = 0; mt < 3; ++mt)
                #pragma unroll
                for (int ns = 0; ns < 4; ++ns) {
                    const half8& bb = ((ks % 3) == 0) ? B0[ns] :
                                      ((ks % 3) == 1) ? B1[ns] : B2[ns];
                    acc[mt][ns] = __builtin_amdgcn_mfma_f32_16x16x32_f16(a[mt], bb, acc[mt][ns], 0, 0, 0);
                }
        }
        #undef LOADB

        // fold group into running argmin (codes ascending; strict <, min-index)
        #pragma unroll
        for (int ns = 0; ns < 4; ++ns) {
            float en = enorm[cb + ns * 16 + tx];
            int   cc = cb + ns * 16 + tx;
            #pragma unroll
            for (int mt = 0; mt < 3; ++mt)
                #pragma unroll
                for (int r = 0; r < 4; ++r) {
                    float d = fmaf(-2.f, acc[mt][ns][r], en);
                    if (d < bd[mt][r]) { bd[mt][r] = d; bi[mt][r] = cc; }
                }
        }
    }

    // reduce across 16 tx lanes (same row, different codes); ties -> min index
    #pragma unroll
    for (int mt = 0; mt < 3; ++mt)
        #pragma unroll
        for (int r = 0; r < 4; ++r) {
            float d = bd[mt][r];
            int   b = bi[mt][r];
            #pragma unroll
            for (int off = 8; off > 0; off >>= 1) {
                float od = __shfl_xor(d, off);
                int   ob = __shfl_xor(b, off);
                if (od < d || (od == d && ob < b)) { d = od; b = ob; }
            }
            bd[mt][r] = d; bi[mt][r] = b;
        }

    // cross-wave reduce via LDS (reuse As)
    __syncthreads();
    float* sd   = (float*)As;          // [48 rows][4 waves]
    int*   si   = ((int*)As) + 192;
    int*   sidx = ((int*)As) + 384;    // final idx per row
    if (tx == 0) {
        #pragma unroll
        for (int mt = 0; mt < 3; ++mt)
            #pragma unroll
            for (int r = 0; r < 4; ++r) {
                int row = mt * 16 + quad * 4 + r;   // C-layout: row = quad*4+reg
                sd[row * 4 + w] = bd[mt][r];
                si[row * 4 + w] = bi[mt][r];
            }
    }
    __syncthreads();
    if (tid < RPB) {
        int row = tid;
        float d = sd[row * 4];
        int   b = si[row * 4];
        #pragma unroll
        for (int ww = 1; ww < 4; ++ww) {
            float od = sd[row * 4 + ww];
            int   ob = si[row * 4 + ww];
            if (od < d || (od == d && ob < b)) { d = od; b = ob; }
        }
        sidx[row] = b;
        if (rbase + row < N_ROWS) {
            out_idx[rbase + row]   = b;
            out_idx_f[rbase + row] = (float)b;
            atomicAdd(&counts_i[b], 1);
        }
    }
    __syncthreads();

    // ---- fused z_q epilogue: z_q_st write + commitment-loss partial
    float l = 0.f;
    #pragma unroll
    for (int u = 0; u < 12; ++u) {
        int gi  = tid + u * 256;       // 0..3071 float4s = 48 rows x 64
        int row = gi >> 6;
        int c4  = gi & 63;
        int grow = rbase + row;
        if (grow < N_ROWS) {
            int k = sidx[row];         // wave-uniform
            float4 zv = *(const float4*)(z    + (size_t)grow * DDIM + c4 * 4);
            float4 ev = *(const float4*)(embf + (size_t)k * DDIM + c4 * 4);
            float dx = ev.x - zv.x, dy = ev.y - zv.y, dz = ev.z - zv.z, dw = ev.w - zv.w;
            float4 o = { zv.x + dx, zv.y + dy, zv.z + dz, zv.w + dw };
            *(float4*)(out_zq + (size_t)grow * DDIM + c4 * 4) = o;
            l += dx * dx + dy * dy + dz * dz + dw * dw;
        }
    }
    #pragma unroll
    for (int off = 32; off > 0; off >>= 1) l += __shfl_down(l, off);
    __shared__ float ls[4];
    if (lane == 0) ls[w] = l;
    __syncthreads();
    if (tid == 0) lossp[blockIdx.x] = ls[0] + ls[1] + ls[2] + ls[3];
}

// ---------------------------------------------------------------------------
// Single block: exclusive prefix-sum of counts -> offsets/cursors; plus the
// ncs/n/loss finalization (merged former k_nsum2).
__global__ __launch_bounds__(256)
void k_scan(const float* __restrict__ cs_in, const int* __restrict__ counts_i,
            const float* __restrict__ lossp, float* __restrict__ out_ncs,
            int* __restrict__ offsets, int* __restrict__ cursors,
            float* __restrict__ n_out, float* __restrict__ loss_out) {
    const int tid = threadIdx.x;
    __shared__ int ps[256];
    int c[4]; int pt = 0;
    #pragma unroll
    for (int i = 0; i < 4; ++i) { c[i] = counts_i[tid * 4 + i]; pt += c[i]; }
    ps[tid] = pt;
    __syncthreads();
    for (int s = 1; s < 256; s <<= 1) {
        int v = (tid >= s) ? ps[tid - s] : 0;
        __syncthreads();
        ps[tid] += v;
        __syncthreads();
    }
    int o = ps[tid] - pt;              // exclusive base for this thread's 4 bins
    float v = 0.f;
    #pragma unroll
    for (int i = 0; i < 4; ++i) {
        offsets[tid * 4 + i] = o;
        cursors[tid * 4 + i] = o;
        o += c[i];
        float nc = cs_in[tid * 4 + i] * 0.99f + 0.01f * (float)c[i];
        out_ncs[tid * 4 + i] = nc;
        v += nc;
    }
    float l = 0.f;
    for (int i = tid; i < NBLK; i += 256) l += lossp[i];
    #pragma unroll
    for (int off = 32; off > 0; off >>= 1) {
        v += __shfl_down(v, off);
        l += __shfl_down(l, off);
    }
    __shared__ float sv[4], sl[4];
    if ((tid & 63) == 0) { sv[tid >> 6] = v; sl[tid >> 6] = l; }
    __syncthreads();
    if (tid == 0) {
        n_out[0]    = sv[0] + sv[1] + sv[2] + sv[3];
        loss_out[0] = 0.25f * ((sl[0] + sl[1] + sl[2] + sl[3]) / 8388608.0f);
    }
}

// ---------------------------------------------------------------------------
// Scatter row ids into per-code contiguous lists (counting sort, phase 2).
__global__ __launch_bounds__(256)
void k_rank(const int* __restrict__ idx, int* __restrict__ cursors,
            int* __restrict__ rows_sorted) {
    int r = blockIdx.x * 256 + threadIdx.x;
    int k = idx[r];
    int pos = atomicAdd(&cursors[k], 1);
    rows_sorted[pos] = r;
}

// ---------------------------------------------------------------------------
// Segment-sum via sorted lists: block per code gathers its ~32 rows coalesced.
__global__ __launch_bounds__(256)
void k_esum(const float* __restrict__ z, const int* __restrict__ rows_sorted,
            const int* __restrict__ offsets, const int* __restrict__ counts_i,
            float* __restrict__ esum) {
    const int k    = blockIdx.x;
    const int tid  = threadIdx.x;
    const int w    = tid >> 6;
    const int lane = tid & 63;
    const int off  = offsets[k];
    const int cnt  = counts_i[k];

    float4 acc = {0.f, 0.f, 0.f, 0.f};
    for (int j = w; j < cnt; j += 4) {
        int row = rows_sorted[off + j];          // wave-uniform broadcast
        float4 zv = *(const float4*)(z + (size_t)row * DDIM + lane * 4);
        acc.x += zv.x; acc.y += zv.y; acc.z += zv.z; acc.w += zv.w;
    }
    __shared__ float sacc[4][DDIM];
    *(float4*)(&sacc[w][lane * 4]) = acc;
    __syncthreads();
    esum[(size_t)k * DDIM + tid] =
        sacc[0][tid] + sacc[1][tid] + sacc[2][tid] + sacc[3][tid];
}

// ---------------------------------------------------------------------------
__global__ __launch_bounds__(256)
void k_embed(const float* __restrict__ ea, const float* __restrict__ esum,
             const float* __restrict__ ncs, const float* __restrict__ n_ws,
             float* __restrict__ out_nea, float* __restrict__ out_nemb) {
    int k = blockIdx.x;
    int d = threadIdx.x;
    size_t off = (size_t)k * DDIM + d;
    float nea = ea[off] * 0.99f + 0.01f * esum[off];
    out_nea[off] = nea;
    float cs = (ncs[k] + 1e-6f) / (n_ws[0] + 0.001024f);   // (ncs+eps)/(n+K*eps)
    out_nemb[off] = nea / cs;
}

// ---------------------------------------------------------------------------
extern "C" void kernel_launch(void* const* d_in, const int* in_sizes, int n_in,
                              void* d_out, int out_size, void* d_ws, size_t ws_size,
                              hipStream_t stream) {
    const float* z   = (const float*)d_in[0];
    const float* emb = (const float*)d_in[1];
    const float* cs  = (const float*)d_in[2];
    const float* ea  = (const float*)d_in[3];
    float* out = (float*)d_out;
    float* ws  = (float*)d_ws;

    float* esum    = ws + W_ESUM;
    float* enorm   = ws + W_ENORM;
    float* lossp   = ws + W_LOSSP;
    int*   cnts    = (int*)(ws + W_CNT);
    int*   offs    = (int*)(ws + W_OFF);
    int*   curs    = (int*)(ws + W_CUR);
    float* wn      = ws + W_N;
    int*   widx    = (int*)(ws + W_IDX);
    int*   rsorted = (int*)(ws + W_SORT);

    // e_hi/e_lo fp16 scratch in the dead O_NEA region, 16B-aligned (+3 floats)
    half_t* ehi = (half_t*)(out + O_NEA + 3);
    half_t* elo = ehi + KCODES * DDIM;

    hipMemsetAsync(cnts, 0, KCODES * sizeof(int), stream);
    k_prep   <<<KCODES, 64, 0, stream>>>(emb, enorm, ehi, elo);
    k_argmin <<<NBLK, 256, 0, stream>>>(z, ehi, elo, enorm, emb,
                                        widx, out + O_IDX, out + O_ZQ, lossp, cnts);
    k_scan   <<<1, 256, 0, stream>>>(cs, cnts, lossp, out + O_NCS, offs, curs,
                                     wn, out + O_LOSS);
    k_rank   <<<N_ROWS / 256, 256, 0, stream>>>(widx, curs, rsorted);
    k_esum   <<<KCODES, 256, 0, stream>>>(z, rsorted, offs, cnts, esum);
    k_embed  <<<KCODES, 256, 0, stream>>>(ea, esum, out + O_NCS, wn,
                                          out + O_NEA, out + O_NEMB);
}

// Round 6
// 392.641 us; speedup vs baseline: 1.7189x; 1.7189x over previous
//
#include <hip/hip_runtime.h>

// Problem constants
#define N_ROWS   32768      // 64*512 flattened z rows
#define KCODES   1024
#define DDIM     256
#define RPB      32         // rows per argmin block: As=32KB -> 4 blocks/CU, grid exact
#define NBLK     1024       // 32768/32

// d_out float offsets (outputs concatenated in reference return order)
#define O_ZQ     0                    // 8388608
#define O_LOSS   8388608              // 1
#define O_IDX    8388609              // 32768
#define O_NCS    8421377              // 1024
#define O_NEA    8422401              // 262144
#define O_NEMB   8684545              // 262144

// workspace float offsets
#define W_ESUM   0                    // 262144
#define W_ENORM  262144               // 1024
#define W_LOSSP  263168               // 1024
#define W_CNT    264192               // 1024 ints (memset to 0)
#define W_OFF    265216               // 1024 ints
#define W_CUR    266240               // 1024 ints
#define W_N      267264               // 1
#define W_IDX    267776               // 32768 ints
#define W_SORT   300544               // 32768 ints

typedef _Float16 half_t;
typedef __attribute__((ext_vector_type(8))) _Float16 half8;
typedef __attribute__((ext_vector_type(4))) _Float16 half4v;
typedef __attribute__((ext_vector_type(4))) float floatx4;

// ---------------------------------------------------------------------------
// ||e_k||^2 + split emb into fp16 hi/lo. 1024 blocks x 64 threads.
__global__ __launch_bounds__(64)
void k_prep(const float* __restrict__ emb, float* __restrict__ enorm,
            half_t* __restrict__ ehi, half_t* __restrict__ elo) {
    int c = blockIdx.x;
    int t = threadIdx.x;
    float4 v = *(const float4*)(emb + c * DDIM + t * 4);
    half4v hi, lo;
    hi[0] = (half_t)v.x; lo[0] = (half_t)(v.x - (float)hi[0]);
    hi[1] = (half_t)v.y; lo[1] = (half_t)(v.y - (float)hi[1]);
    hi[2] = (half_t)v.z; lo[2] = (half_t)(v.z - (float)hi[2]);
    hi[3] = (half_t)v.w; lo[3] = (half_t)(v.w - (float)hi[3]);
    *(half4v*)(ehi + c * DDIM + t * 4) = hi;
    *(half4v*)(elo + c * DDIM + t * 4) = lo;
    float s = v.x * v.x + v.y * v.y + v.z * v.z + v.w * v.w;
    #pragma unroll
    for (int off = 32; off > 0; off >>= 1) s += __shfl_down(s, off);
    if (t == 0) enorm[c] = s;
}

// ---------------------------------------------------------------------------
// MFMA argmin, small-footprint edition. dist(r,c) = ||e_c||^2 - 2 z_r.e_c,
// dot via fp16 hi/lo K-concat (K'=768): segs 0:hi.hi 1:hi.lo 2:lo.hi.
// Block: 32 rows, 256 thr, As 32KB staged once (barrier-free K-loop after).
// Wave w owns codes [w*256,(w+1)*256): 8 groups of 32 codes; per step
// 2 m-tiles x 2 n-subtiles of 16x16x32 MFMA; depth-2 rotating B prefetch
// straight from global (L2-resident). Register arrays ~64 VGPR by design --
// round-4/5 lesson: 256-VGPR waves ran at ~1 wave/SIMD (Occupancy 11%) and
// launch_bounds coercion spilled (605MB scratch writes). No coercion here.
__global__ __launch_bounds__(256)
void k_argmin(const float* __restrict__ z, const half_t* __restrict__ ehi,
              const half_t* __restrict__ elo, const float* __restrict__ enorm,
              const float* __restrict__ embf,
              int* __restrict__ out_idx, float* __restrict__ out_idx_f,
              float* __restrict__ out_zq, float* __restrict__ lossp,
              int* __restrict__ counts_i) {
    __shared__ __align__(16) half_t As[RPB * 512];   // 32 KB

    const int tid  = threadIdx.x;
    const int w    = tid >> 6;
    const int lane = tid & 63;
    const int tx   = lane & 15;
    const int quad = lane >> 4;
    const int rbase = blockIdx.x * RPB;

    // ---- stage A: read z fp32, split hi/lo in-register, swizzled LDS store
    #pragma unroll
    for (int it = 0; it < 4; ++it) {
        int f   = tid + it * 256;
        int row = f >> 5;             // 0..31
        int g   = f & 31;
        const float* zp = z + (size_t)(rbase + row) * DDIM + g * 8;
        float4 v0 = *(const float4*)zp;
        float4 v1 = *(const float4*)(zp + 4);
        half8 hi, lo;
        hi[0] = (half_t)v0.x; lo[0] = (half_t)(v0.x - (float)hi[0]);
        hi[1] = (half_t)v0.y; lo[1] = (half_t)(v0.y - (float)hi[1]);
        hi[2] = (half_t)v0.z; lo[2] = (half_t)(v0.z - (float)hi[2]);
        hi[3] = (half_t)v0.w; lo[3] = (half_t)(v0.w - (float)hi[3]);
        hi[4] = (half_t)v1.x; lo[4] = (half_t)(v1.x - (float)hi[4]);
        hi[5] = (half_t)v1.y; lo[5] = (half_t)(v1.y - (float)hi[5]);
        hi[6] = (half_t)v1.z; lo[6] = (half_t)(v1.z - (float)hi[6]);
        hi[7] = (half_t)v1.w; lo[7] = (half_t)(v1.w - (float)hi[7]);
        int sw = row & 7;
        *(half8*)(&As[row * 512 + ((g ^ sw)) * 8])        = hi;  // k8 = g
        *(half8*)(&As[row * 512 + (((32 + g) ^ sw)) * 8]) = lo;  // k8 = 32+g
    }
    __syncthreads();                  // the ONLY main-loop barrier

    floatx4 zero4 = {0.f, 0.f, 0.f, 0.f};
    float bd[2][4];
    int   bi[2][4];
    #pragma unroll
    for (int mt = 0; mt < 2; ++mt)
        #pragma unroll
        for (int r = 0; r < 4; ++r) { bd[mt][r] = 3.402823466e38f; bi[mt][r] = 0; }

    for (int g8 = 0; g8 < 8; ++g8) {
        const int cb = w * 256 + g8 * 32;
        floatx4 acc[2][2];
        #pragma unroll
        for (int mt = 0; mt < 2; ++mt)
            #pragma unroll
            for (int ns = 0; ns < 2; ++ns) acc[mt][ns] = zero4;

        size_t crow[2];
        #pragma unroll
        for (int ns = 0; ns < 2; ++ns)
            crow[ns] = (size_t)(cb + ns * 16 + tx) * DDIM + quad * 8;

        // depth-2 rotating B prefetch: seg c = ks>>3 (0:hi.hi 1:hi.lo 2:lo.hi)
        half8 B0[2], B1[2], B2[2];
        #define LOADB(P, BUF)                                                  \
            {   const half_t* srcp = (((P) >> 3) == 1) ? elo : ehi;            \
                const int koffp = ((P) & 7) * 32;                              \
                _Pragma("unroll")                                              \
                for (int ns = 0; ns < 2; ++ns)                                 \
                    BUF[ns] = *(const half8*)(srcp + crow[ns] + koffp); }
        LOADB(0, B0);
        LOADB(1, B1);

        #pragma unroll
        for (int ks = 0; ks < 24; ++ks) {
            if (ks + 2 < 24) {
                if ((ks % 3) == 0)      { LOADB(ks + 2, B2); }
                else if ((ks % 3) == 1) { LOADB(ks + 2, B0); }
                else                    { LOADB(ks + 2, B1); }
            }
            const int c   = ks >> 3;
            const int k8b = (c == 2 ? 32 : 0) + (ks & 7) * 4;
            half8 a[2];
            #pragma unroll
            for (int mt = 0; mt < 2; ++mt) {
                int row = mt * 16 + tx;
                a[mt] = *(half8*)(&As[row * 512 + ((k8b + quad) ^ (row & 7)) * 8]);
            }
            #pragma unroll
            for (int mt = 0; mt < 2; ++mt)
                #pragma unroll
                for (int ns = 0; ns < 2; ++ns) {
                    const half8& bb = ((ks % 3) == 0) ? B0[ns] :
                                      ((ks % 3) == 1) ? B1[ns] : B2[ns];
                    acc[mt][ns] = __builtin_amdgcn_mfma_f32_16x16x32_f16(a[mt], bb, acc[mt][ns], 0, 0, 0);
                }
        }
        #undef LOADB

        // fold group into running argmin (codes ascending; strict <, min-index)
        #pragma unroll
        for (int ns = 0; ns < 2; ++ns) {
            float en = enorm[cb + ns * 16 + tx];
            int   cc = cb + ns * 16 + tx;
            #pragma unroll
            for (int mt = 0; mt < 2; ++mt)
                #pragma unroll
                for (int r = 0; r < 4; ++r) {
                    float d = fmaf(-2.f, acc[mt][ns][r], en);
                    if (d < bd[mt][r]) { bd[mt][r] = d; bi[mt][r] = cc; }
                }
        }
    }

    // reduce across 16 tx lanes (same row, different codes); ties -> min index
    #pragma unroll
    for (int mt = 0; mt < 2; ++mt)
        #pragma unroll
        for (int r = 0; r < 4; ++r) {
            float d = bd[mt][r];
            int   b = bi[mt][r];
            #pragma unroll
            for (int off = 8; off > 0; off >>= 1) {
                float od = __shfl_xor(d, off);
                int   ob = __shfl_xor(b, off);
                if (od < d || (od == d && ob < b)) { d = od; b = ob; }
            }
            bd[mt][r] = d; bi[mt][r] = b;
        }

    // cross-wave reduce via LDS (reuse As)
    __syncthreads();
    float* sd   = (float*)As;          // [32 rows][4 waves]
    int*   si   = ((int*)As) + 128;
    int*   sidx = ((int*)As) + 256;    // final idx per row
    if (tx == 0) {
        #pragma unroll
        for (int mt = 0; mt < 2; ++mt)
            #pragma unroll
            for (int r = 0; r < 4; ++r) {
                int row = mt * 16 + quad * 4 + r;   // C-layout: row = quad*4+reg
                sd[row * 4 + w] = bd[mt][r];
                si[row * 4 + w] = bi[mt][r];
            }
    }
    __syncthreads();
    if (tid < RPB) {
        int row = tid;
        float d = sd[row * 4];
        int   b = si[row * 4];
        #pragma unroll
        for (int ww = 1; ww < 4; ++ww) {
            float od = sd[row * 4 + ww];
            int   ob = si[row * 4 + ww];
            if (od < d || (od == d && ob < b)) { d = od; b = ob; }
        }
        sidx[row] = b;
        out_idx[rbase + row]   = b;
        out_idx_f[rbase + row] = (float)b;
        atomicAdd(&counts_i[b], 1);
    }
    __syncthreads();

    // ---- fused z_q epilogue: z_q_st write + commitment-loss partial
    float l = 0.f;
    #pragma unroll
    for (int u = 0; u < 8; ++u) {
        int gi  = tid + u * 256;       // 0..2047 float4s = 32 rows x 64
        int row = gi >> 6;
        int c4  = gi & 63;
        int k   = sidx[row];           // wave-uniform
        float4 zv = *(const float4*)(z    + (size_t)(rbase + row) * DDIM + c4 * 4);
        float4 ev = *(const float4*)(embf + (size_t)k * DDIM + c4 * 4);
        float dx = ev.x - zv.x, dy = ev.y - zv.y, dz = ev.z - zv.z, dw = ev.w - zv.w;
        float4 o = { zv.x + dx, zv.y + dy, zv.z + dz, zv.w + dw };  // z + (z_q - z)
        *(float4*)(out_zq + (size_t)(rbase + row) * DDIM + c4 * 4) = o;
        l += dx * dx + dy * dy + dz * dz + dw * dw;
    }
    #pragma unroll
    for (int off = 32; off > 0; off >>= 1) l += __shfl_down(l, off);
    __shared__ float ls[4];
    if (lane == 0) ls[w] = l;
    __syncthreads();
    if (tid == 0) lossp[blockIdx.x] = ls[0] + ls[1] + ls[2] + ls[3];
}

// ---------------------------------------------------------------------------
// Single block: exclusive prefix-sum of counts -> offsets/cursors; plus the
// ncs/n/loss finalization.
__global__ __launch_bounds__(256)
void k_scan(const float* __restrict__ cs_in, const int* __restrict__ counts_i,
            const float* __restrict__ lossp, float* __restrict__ out_ncs,
            int* __restrict__ offsets, int* __restrict__ cursors,
            float* __restrict__ n_out, float* __restrict__ loss_out) {
    const int tid = threadIdx.x;
    __shared__ int ps[256];
    int c[4]; int pt = 0;
    #pragma unroll
    for (int i = 0; i < 4; ++i) { c[i] = counts_i[tid * 4 + i]; pt += c[i]; }
    ps[tid] = pt;
    __syncthreads();
    for (int s = 1; s < 256; s <<= 1) {
        int v = (tid >= s) ? ps[tid - s] : 0;
        __syncthreads();
        ps[tid] += v;
        __syncthreads();
    }
    int o = ps[tid] - pt;              // exclusive base for this thread's 4 bins
    float v = 0.f;
    #pragma unroll
    for (int i = 0; i < 4; ++i) {
        offsets[tid * 4 + i] = o;
        cursors[tid * 4 + i] = o;
        o += c[i];
        float nc = cs_in[tid * 4 + i] * 0.99f + 0.01f * (float)c[i];
        out_ncs[tid * 4 + i] = nc;
        v += nc;
    }
    float l = 0.f;
    for (int i = tid; i < NBLK; i += 256) l += lossp[i];
    #pragma unroll
    for (int off = 32; off > 0; off >>= 1) {
        v += __shfl_down(v, off);
        l += __shfl_down(l, off);
    }
    __shared__ float sv[4], sl[4];
    if ((tid & 63) == 0) { sv[tid >> 6] = v; sl[tid >> 6] = l; }
    __syncthreads();
    if (tid == 0) {
        n_out[0]    = sv[0] + sv[1] + sv[2] + sv[3];
        loss_out[0] = 0.25f * ((sl[0] + sl[1] + sl[2] + sl[3]) / 8388608.0f);
    }
}

// ---------------------------------------------------------------------------
// Scatter row ids into per-code contiguous lists (counting sort, phase 2).
__global__ __launch_bounds__(256)
void k_rank(const int* __restrict__ idx, int* __restrict__ cursors,
            int* __restrict__ rows_sorted) {
    int r = blockIdx.x * 256 + threadIdx.x;
    int k = idx[r];
    int pos = atomicAdd(&cursors[k], 1);
    rows_sorted[pos] = r;
}

// ---------------------------------------------------------------------------
// Segment-sum via sorted lists: block per code gathers its ~32 rows coalesced.
__global__ __launch_bounds__(256)
void k_esum(const float* __restrict__ z, const int* __restrict__ rows_sorted,
            const int* __restrict__ offsets, const int* __restrict__ counts_i,
            float* __restrict__ esum) {
    const int k    = blockIdx.x;
    const int tid  = threadIdx.x;
    const int w    = tid >> 6;
    const int lane = tid & 63;
    const int off  = offsets[k];
    const int cnt  = counts_i[k];

    float4 acc = {0.f, 0.f, 0.f, 0.f};
    for (int j = w; j < cnt; j += 4) {
        int row = rows_sorted[off + j];          // wave-uniform broadcast
        float4 zv = *(const float4*)(z + (size_t)row * DDIM + lane * 4);
        acc.x += zv.x; acc.y += zv.y; acc.z += zv.z; acc.w += zv.w;
    }
    __shared__ float sacc[4][DDIM];
    *(float4*)(&sacc[w][lane * 4]) = acc;
    __syncthreads();
    esum[(size_t)k * DDIM + tid] =
        sacc[0][tid] + sacc[1][tid] + sacc[2][tid] + sacc[3][tid];
}

// ---------------------------------------------------------------------------
__global__ __launch_bounds__(256)
void k_embed(const float* __restrict__ ea, const float* __restrict__ esum,
             const float* __restrict__ ncs, const float* __restrict__ n_ws,
             float* __restrict__ out_nea, float* __restrict__ out_nemb) {
    int k = blockIdx.x;
    int d = threadIdx.x;
    size_t off = (size_t)k * DDIM + d;
    float nea = ea[off] * 0.99f + 0.01f * esum[off];
    out_nea[off] = nea;
    float cs = (ncs[k] + 1e-6f) / (n_ws[0] + 0.001024f);   // (ncs+eps)/(n+K*eps)
    out_nemb[off] = nea / cs;
}

// ---------------------------------------------------------------------------
extern "C" void kernel_launch(void* const* d_in, const int* in_sizes, int n_in,
                              void* d_out, int out_size, void* d_ws, size_t ws_size,
                              hipStream_t stream) {
    const float* z   = (const float*)d_in[0];
    const float* emb = (const float*)d_in[1];
    const float* cs  = (const float*)d_in[2];
    const float* ea  = (const float*)d_in[3];
    float* out = (float*)d_out;
    float* ws  = (float*)d_ws;

    float* esum    = ws + W_ESUM;
    float* enorm   = ws + W_ENORM;
    float* lossp   = ws + W_LOSSP;
    int*   cnts    = (int*)(ws + W_CNT);
    int*   offs    = (int*)(ws + W_OFF);
    int*   curs    = (int*)(ws + W_CUR);
    float* wn      = ws + W_N;
    int*   widx    = (int*)(ws + W_IDX);
    int*   rsorted = (int*)(ws + W_SORT);

    // e_hi/e_lo fp16 scratch in the dead O_NEA region, 16B-aligned (+3 floats)
    half_t* ehi = (half_t*)(out + O_NEA + 3);
    half_t* elo = ehi + KCODES * DDIM;

    hipMemsetAsync(cnts, 0, KCODES * sizeof(int), stream);
    k_prep   <<<KCODES, 64, 0, stream>>>(emb, enorm, ehi, elo);
    k_argmin <<<NBLK, 256, 0, stream>>>(z, ehi, elo, enorm, emb,
                                        widx, out + O_IDX, out + O_ZQ, lossp, cnts);
    k_scan   <<<1, 256, 0, stream>>>(cs, cnts, lossp, out + O_NCS, offs, curs,
                                     wn, out + O_LOSS);
    k_rank   <<<N_ROWS / 256, 256, 0, stream>>>(widx, curs, rsorted);
    k_esum   <<<KCODES, 256, 0, stream>>>(z, rsorted, offs, cnts, esum);
    k_embed  <<<KCODES, 256, 0, stream>>>(ea, esum, out + O_NCS, wn,
                                          out + O_NEA, out + O_NEMB);
}

// Round 7
// 311.045 us; speedup vs baseline: 2.1698x; 1.2623x over previous
//
#include <hip/hip_runtime.h>

// Problem constants
#define N_ROWS   32768      // 64*512 flattened z rows
#define KCODES   1024
#define DDIM     256
#define RPB      64         // rows per argmin block: As=64KB -> 2 blocks/CU
#define NBLK     512        // 32768/64

// d_out float offsets (outputs concatenated in reference return order)
#define O_ZQ     0                    // 8388608
#define O_LOSS   8388608              // 1
#define O_IDX    8388609              // 32768
#define O_NCS    8421377              // 1024
#define O_NEA    8422401              // 262144
#define O_NEMB   8684545              // 262144

// workspace float offsets
#define W_ESUM   0                    // 262144 (memset, together with CNT)
#define W_CNT    262144               // 1024 ints (memset)
#define W_ENORM  263168               // 1024
#define W_LOSSP  264192               // 512
#define W_CUR    264704               // 1024 ints
#define W_N      265728               // 1 (padded to 265792)
#define W_IDX    265792               // 32768 ints
#define W_SORT   298560               // 32768 ints
// total 331328 floats ~= 1.26 MB (<= round-5/6 footprint)

typedef _Float16 half_t;
typedef __attribute__((ext_vector_type(8))) _Float16 half8;
typedef __attribute__((ext_vector_type(4))) float floatx4;

// ---------------------------------------------------------------------------
// Pack B into MFMA-native fragment order + compute ||e||^2.
// Bp[ct][ks][lane][8]: ct=16-code tile (64), ks=k-step (24 = 3 segs x 8),
// lane: col=lane&15 (code in tile), k=(lane>>4)*8+j. seg 0:hi 1:lo 2:hi.
// A wave's B-frag load in k_argmin becomes ONE coalesced 1KB dwordx4 load
// (round-6 killer: 16-way-scattered B gathers + 1.6GB L2 traffic).
__global__ __launch_bounds__(256)
void k_prep2(const float* __restrict__ emb, float* __restrict__ enorm,
             half_t* __restrict__ Bp) {
    __shared__ half_t hi[16 * 256];
    __shared__ half_t lo[16 * 256];
    __shared__ float  ssum[256];
    const int ct  = blockIdx.x;       // 16-code tile
    const int tid = threadIdx.x;
    const int c16 = tid >> 4;         // code within tile
    const int dp  = tid & 15;         // 16-dim part

    float ss = 0.f;
    #pragma unroll
    for (int i = 0; i < 4; ++i) {
        float4 v = *(const float4*)(emb + (size_t)(ct * 16 + c16) * DDIM + dp * 16 + i * 4);
        ss += v.x * v.x + v.y * v.y + v.z * v.z + v.w * v.w;
        #pragma unroll
        for (int q = 0; q < 4; ++q) {
            float f = (&v.x)[q];
            half_t h = (half_t)f;
            hi[c16 * 256 + dp * 16 + i * 4 + q] = h;
            lo[c16 * 256 + dp * 16 + i * 4 + q] = (half_t)(f - (float)h);
        }
    }
    ssum[tid] = ss;
    __syncthreads();
    if (tid < 16) {
        float s = 0.f;
        #pragma unroll
        for (int i = 0; i < 16; ++i) s += ssum[tid * 16 + i];
        enorm[ct * 16 + tid] = s;
    }

    // write phase: 24 steps x 64 lanes x 8 halfs
    #pragma unroll
    for (int i = 0; i < 6; ++i) {
        int f    = tid + i * 256;     // 0..1535
        int ks   = f >> 6;
        int lane = f & 63;
        int cc   = lane & 15;
        int seg  = ks >> 3;
        int ko   = (ks & 7) * 32 + (lane >> 4) * 8;
        const half_t* src = (seg == 1) ? lo : hi;
        half8 v = *(const half8*)(src + cc * 256 + ko);
        *(half8*)(Bp + ((size_t)(ct * 24 + ks) * 64 + lane) * 8) = v;
    }
}

// ---------------------------------------------------------------------------
// MFMA argmin. dist(r,c)=||e||^2-2 z.e; fp16 hi/lo K-concat (K'=768).
// Block: 64 rows, 256 thr; As 64KB staged once; barrier-free K-loop.
// Wave w owns codes [w*256,(w+1)*256): 4 groups x (4m x 4n) 16x16x32 MFMA;
// depth-2 rotating B prefetch of PACKED coalesced 1KB frags. LDS 64KB ->
// 2 blocks/CU -> 8 waves/CU; VGPR<=256 is free at that occupancy, so no
// aggressive launch_bounds (round-5 lesson: coercion => 605MB spills).
__global__ __launch_bounds__(256, 2)
void k_argmin(const float* __restrict__ z, const half_t* __restrict__ Bp,
              const float* __restrict__ enorm, const float* __restrict__ embf,
              int* __restrict__ out_idx, float* __restrict__ out_idx_f,
              float* __restrict__ out_zq, float* __restrict__ lossp,
              int* __restrict__ counts_i) {
    __shared__ __align__(16) half_t As[RPB * 512];   // 64 KB

    const int tid  = threadIdx.x;
    const int w    = tid >> 6;
    const int lane = tid & 63;
    const int tx   = lane & 15;
    const int quad = lane >> 4;
    const int rbase = blockIdx.x * RPB;

    // ---- stage A: read z fp32, split hi/lo in-register, swizzled LDS store
    #pragma unroll
    for (int it = 0; it < 8; ++it) {
        int f   = tid + it * 256;
        int row = f >> 5;             // 0..63
        int g   = f & 31;
        const float* zp = z + (size_t)(rbase + row) * DDIM + g * 8;
        float4 v0 = *(const float4*)zp;
        float4 v1 = *(const float4*)(zp + 4);
        half8 hi, lo;
        hi[0] = (half_t)v0.x; lo[0] = (half_t)(v0.x - (float)hi[0]);
        hi[1] = (half_t)v0.y; lo[1] = (half_t)(v0.y - (float)hi[1]);
        hi[2] = (half_t)v0.z; lo[2] = (half_t)(v0.z - (float)hi[2]);
        hi[3] = (half_t)v0.w; lo[3] = (half_t)(v0.w - (float)hi[3]);
        hi[4] = (half_t)v1.x; lo[4] = (half_t)(v1.x - (float)hi[4]);
        hi[5] = (half_t)v1.y; lo[5] = (half_t)(v1.y - (float)hi[5]);
        hi[6] = (half_t)v1.z; lo[6] = (half_t)(v1.z - (float)hi[6]);
        hi[7] = (half_t)v1.w; lo[7] = (half_t)(v1.w - (float)hi[7]);
        int sw = row & 7;
        *(half8*)(&As[row * 512 + ((g ^ sw)) * 8])        = hi;  // k8 = g
        *(half8*)(&As[row * 512 + (((32 + g) ^ sw)) * 8]) = lo;  // k8 = 32+g
    }
    __syncthreads();                  // the ONLY main-loop barrier

    floatx4 zero4 = {0.f, 0.f, 0.f, 0.f};
    float bd[4][4];
    int   bi[4][4];
    #pragma unroll
    for (int mt = 0; mt < 4; ++mt)
        #pragma unroll
        for (int r = 0; r < 4; ++r) { bd[mt][r] = 3.402823466e38f; bi[mt][r] = 0; }

    for (int g4 = 0; g4 < 4; ++g4) {
        const int cb = w * 256 + g4 * 64;
        // wave's 4 tiles this group: global ct = w*16 + g4*4 + ns
        const half_t* Bg = Bp + ((size_t)(w * 16 + g4 * 4) * 24 * 64 + lane) * 8;

        floatx4 acc[4][4];
        #pragma unroll
        for (int mt = 0; mt < 4; ++mt)
            #pragma unroll
            for (int ns = 0; ns < 4; ++ns) acc[mt][ns] = zero4;

        half8 B0[4], B1[4], B2[4];
        #define LOADB(P, BUF)                                                  \
            { _Pragma("unroll")                                                \
              for (int ns = 0; ns < 4; ++ns)                                   \
                  BUF[ns] = *(const half8*)(Bg + (size_t)(ns * 24 + (P)) * 512); }
        LOADB(0, B0);
        LOADB(1, B1);

        #pragma unroll
        for (int ks = 0; ks < 24; ++ks) {
            if (ks + 2 < 24) {
                if ((ks % 3) == 0)      { LOADB(ks + 2, B2); }
                else if ((ks % 3) == 1) { LOADB(ks + 2, B0); }
                else                    { LOADB(ks + 2, B1); }
            }
            const int c   = ks >> 3;
            const int k8b = (c == 2 ? 32 : 0) + (ks & 7) * 4;
            half8 a[4];
            #pragma unroll
            for (int mt = 0; mt < 4; ++mt) {
                int row = mt * 16 + tx;
                a[mt] = *(half8*)(&As[row * 512 + ((k8b + quad) ^ (row & 7)) * 8]);
            }
            #pragma unroll
            for (int mt = 0; mt < 4; ++mt)
                #pragma unroll
                for (int ns = 0; ns < 4; ++ns) {
                    const half8& bb = ((ks % 3) == 0) ? B0[ns] :
                                      ((ks % 3) == 1) ? B1[ns] : B2[ns];
                    acc[mt][ns] = __builtin_amdgcn_mfma_f32_16x16x32_f16(a[mt], bb, acc[mt][ns], 0, 0, 0);
                }
        }
        #undef LOADB

        // fold group into running argmin (codes ascending; strict <, min-index)
        #pragma unroll
        for (int ns = 0; ns < 4; ++ns) {
            float en = enorm[cb + ns * 16 + tx];
            int   cc = cb + ns * 16 + tx;
            #pragma unroll
            for (int mt = 0; mt < 4; ++mt)
                #pragma unroll
                for (int r = 0; r < 4; ++r) {
                    float d = fmaf(-2.f, acc[mt][ns][r], en);
                    if (d < bd[mt][r]) { bd[mt][r] = d; bi[mt][r] = cc; }
                }
        }
    }

    // reduce across 16 tx lanes (same row, different codes); ties -> min index
    #pragma unroll
    for (int mt = 0; mt < 4; ++mt)
        #pragma unroll
        for (int r = 0; r < 4; ++r) {
            float d = bd[mt][r];
            int   b = bi[mt][r];
            #pragma unroll
            for (int off = 8; off > 0; off >>= 1) {
                float od = __shfl_xor(d, off);
                int   ob = __shfl_xor(b, off);
                if (od < d || (od == d && ob < b)) { d = od; b = ob; }
            }
            bd[mt][r] = d; bi[mt][r] = b;
        }

    // cross-wave reduce via LDS (reuse As)
    __syncthreads();
    float* sd   = (float*)As;          // [64 rows][4 waves]
    int*   si   = ((int*)As) + 256;
    int*   sidx = ((int*)As) + 512;    // final idx per row
    if (tx == 0) {
        #pragma unroll
        for (int mt = 0; mt < 4; ++mt)
            #pragma unroll
            for (int r = 0; r < 4; ++r) {
                int row = mt * 16 + quad * 4 + r;   // C-layout: row = quad*4+reg
                sd[row * 4 + w] = bd[mt][r];
                si[row * 4 + w] = bi[mt][r];
            }
    }
    __syncthreads();
    if (tid < RPB) {
        int row = tid;
        float d = sd[row * 4];
        int   b = si[row * 4];
        #pragma unroll
        for (int ww = 1; ww < 4; ++ww) {
            float od = sd[row * 4 + ww];
            int   ob = si[row * 4 + ww];
            if (od < d || (od == d && ob < b)) { d = od; b = ob; }
        }
        sidx[row] = b;
        out_idx[rbase + row]   = b;
        out_idx_f[rbase + row] = (float)b;
        atomicAdd(&counts_i[b], 1);
    }
    __syncthreads();

    // ---- fused z_q epilogue: z_q_st write + commitment-loss partial
    float l = 0.f;
    #pragma unroll
    for (int u = 0; u < 16; ++u) {
        int gi  = tid + u * 256;       // 0..4095 float4s = 64 rows x 64
        int row = gi >> 6;
        int c4  = gi & 63;
        int k   = sidx[row];           // wave-uniform
        float4 zv = *(const float4*)(z    + (size_t)(rbase + row) * DDIM + c4 * 4);
        float4 ev = *(const float4*)(embf + (size_t)k * DDIM + c4 * 4);
        float dx = ev.x - zv.x, dy = ev.y - zv.y, dz = ev.z - zv.z, dw = ev.w - zv.w;
        float4 o = { zv.x + dx, zv.y + dy, zv.z + dz, zv.w + dw };  // z + (z_q - z)
        *(float4*)(out_zq + (size_t)(rbase + row) * DDIM + c4 * 4) = o;
        l += dx * dx + dy * dy + dz * dz + dw * dw;
    }
    #pragma unroll
    for (int off = 32; off > 0; off >>= 1) l += __shfl_down(l, off);
    __shared__ float ls[4];
    if (lane == 0) ls[w] = l;
    __syncthreads();
    if (tid == 0) lossp[blockIdx.x] = ls[0] + ls[1] + ls[2] + ls[3];
}

// ---------------------------------------------------------------------------
// Single block: prefix-sum counts -> cursors; ncs/n/loss finalization.
__global__ __launch_bounds__(256)
void k_scan(const float* __restrict__ cs_in, const int* __restrict__ counts_i,
            const float* __restrict__ lossp, float* __restrict__ out_ncs,
            int* __restrict__ cursors,
            float* __restrict__ n_out, float* __restrict__ loss_out) {
    const int tid = threadIdx.x;
    __shared__ int ps[256];
    int c[4]; int pt = 0;
    #pragma unroll
    for (int i = 0; i < 4; ++i) { c[i] = counts_i[tid * 4 + i]; pt += c[i]; }
    ps[tid] = pt;
    __syncthreads();
    for (int s = 1; s < 256; s <<= 1) {
        int v = (tid >= s) ? ps[tid - s] : 0;
        __syncthreads();
        ps[tid] += v;
        __syncthreads();
    }
    int o = ps[tid] - pt;              // exclusive base for this thread's 4 bins
    float v = 0.f;
    #pragma unroll
    for (int i = 0; i < 4; ++i) {
        cursors[tid * 4 + i] = o;
        o += c[i];
        float nc = cs_in[tid * 4 + i] * 0.99f + 0.01f * (float)c[i];
        out_ncs[tid * 4 + i] = nc;
        v += nc;
    }
    float l = 0.f;
    for (int i = tid; i < NBLK; i += 256) l += lossp[i];
    #pragma unroll
    for (int off = 32; off > 0; off >>= 1) {
        v += __shfl_down(v, off);
        l += __shfl_down(l, off);
    }
    __shared__ float sv[4], sl[4];
    if ((tid & 63) == 0) { sv[tid >> 6] = v; sl[tid >> 6] = l; }
    __syncthreads();
    if (tid == 0) {
        n_out[0]    = sv[0] + sv[1] + sv[2] + sv[3];
        loss_out[0] = 0.25f * ((sl[0] + sl[1] + sl[2] + sl[3]) / 8388608.0f);
    }
}

// ---------------------------------------------------------------------------
// Scatter row ids into per-code contiguous lists (counting sort, phase 2).
__global__ __launch_bounds__(256)
void k_rank(const int* __restrict__ idx, int* __restrict__ cursors,
            int* __restrict__ rows_sorted) {
    int r = blockIdx.x * 256 + threadIdx.x;
    int k = idx[r];
    int pos = atomicAdd(&cursors[k], 1);
    rows_sorted[pos] = r;
}

// ---------------------------------------------------------------------------
// Skew-proof segment-sum: each wave owns exactly 64 sorted positions,
// accumulates equal-code runs in registers, flushes runs via fp32 atomics
// (~1.5K flushes total). No per-code blocks -> no hot-code serialization
// (round-6 killer: skewed counts made one block do ~1000 serial row loads).
__global__ __launch_bounds__(128)
void k_esum2(const float* __restrict__ z, const int* __restrict__ rows_sorted,
             const int* __restrict__ idx, float* __restrict__ esum) {
    const int tid  = threadIdx.x;
    const int w    = tid >> 6;
    const int lane = tid & 63;
    const int base = (blockIdx.x * 2 + w) * 64;   // 256 blocks x 2 waves

    int r = rows_sorted[base + lane];
    int c = idx[r];
    float4 acc = {0.f, 0.f, 0.f, 0.f};
    #pragma unroll 8
    for (int j = 0; j < 64; ++j) {
        int rj = __shfl(r, j);
        int cj = __shfl(c, j);
        float4 zv = *(const float4*)(z + (size_t)rj * DDIM + lane * 4);
        acc.x += zv.x; acc.y += zv.y; acc.z += zv.z; acc.w += zv.w;
        int cn = (j < 63) ? __shfl(c, j + 1) : -1;
        if (cn != cj) {                // wave-uniform branch
            float* p = esum + (size_t)cj * DDIM + lane * 4;
            atomicAdd(p + 0, acc.x);
            atomicAdd(p + 1, acc.y);
            atomicAdd(p + 2, acc.z);
            atomicAdd(p + 3, acc.w);
            acc.x = 0.f; acc.y = 0.f; acc.z = 0.f; acc.w = 0.f;
        }
    }
}

// ---------------------------------------------------------------------------
__global__ __launch_bounds__(256)
void k_embed(const float* __restrict__ ea, const float* __restrict__ esum,
             const float* __restrict__ ncs, const float* __restrict__ n_ws,
             float* __restrict__ out_nea, float* __restrict__ out_nemb) {
    int k = blockIdx.x;
    int d = threadIdx.x;
    size_t off = (size_t)k * DDIM + d;
    float nea = ea[off] * 0.99f + 0.01f * esum[off];
    out_nea[off] = nea;
    float cs = (ncs[k] + 1e-6f) / (n_ws[0] + 0.001024f);   // (ncs+eps)/(n+K*eps)
    out_nemb[off] = nea / cs;
}

// ---------------------------------------------------------------------------
extern "C" void kernel_launch(void* const* d_in, const int* in_sizes, int n_in,
                              void* d_out, int out_size, void* d_ws, size_t ws_size,
                              hipStream_t stream) {
    const float* z   = (const float*)d_in[0];
    const float* emb = (const float*)d_in[1];
    const float* cs  = (const float*)d_in[2];
    const float* ea  = (const float*)d_in[3];
    float* out = (float*)d_out;
    float* ws  = (float*)d_ws;

    float* esum    = ws + W_ESUM;
    int*   cnts    = (int*)(ws + W_CNT);
    float* enorm   = ws + W_ENORM;
    float* lossp   = ws + W_LOSSP;
    int*   curs    = (int*)(ws + W_CUR);
    float* wn      = ws + W_N;
    int*   widx    = (int*)(ws + W_IDX);
    int*   rsorted = (int*)(ws + W_SORT);

    // packed-B fp16 scratch in dead O_NEA/O_NEMB output region (16B-aligned;
    // k_embed, the only writer of that region, runs last)
    half_t* Bp = (half_t*)(out + O_NEA + 3);   // 786432 halfs

    hipMemsetAsync(ws, 0, (size_t)(262144 + 1024) * sizeof(float), stream);
    k_prep2  <<<64, 256, 0, stream>>>(emb, enorm, Bp);
    k_argmin <<<NBLK, 256, 0, stream>>>(z, Bp, enorm, emb,
                                        widx, out + O_IDX, out + O_ZQ, lossp, cnts);
    k_scan   <<<1, 256, 0, stream>>>(cs, cnts, lossp, out + O_NCS, curs,
                                     wn, out + O_LOSS);
    k_rank   <<<N_ROWS / 256, 256, 0, stream>>>(widx, curs, rsorted);
    k_esum2  <<<256, 128, 0, stream>>>(z, rsorted, widx, esum);
    k_embed  <<<KCODES, 256, 0, stream>>>(ea, esum, out + O_NCS, wn,
                                          out + O_NEA, out + O_NEMB);
}

// Round 8
// 260.423 us; speedup vs baseline: 2.5916x; 1.1944x over previous
//
#include <hip/hip_runtime.h>

// Problem constants
#define N_ROWS   32768      // 64*512 flattened z rows
#define KCODES   1024
#define DDIM     256
#define RPB      64         // rows per argmin block: As=64KB -> 2 blocks/CU
#define NBLK     512        // 32768/64

// d_out float offsets (outputs concatenated in reference return order)
#define O_ZQ     0                    // 8388608
#define O_LOSS   8388608              // 1
#define O_IDX    8388609              // 32768
#define O_NCS    8421377              // 1024
#define O_NEA    8422401              // 262144
#define O_NEMB   8684545              // 262144

// workspace float offsets
#define W_ESUM   0                    // 262144 (memset, together with CNT)
#define W_CNT    262144               // 1024 ints (memset)
#define W_ENORM  263168               // 1024
#define W_LOSSP  264192               // 512
#define W_CUR    264704               // 1024 ints
#define W_N      265728               // 1
#define W_IDX    265792               // 32768 ints
#define W_SORT   298560               // 32768 ints

typedef _Float16 half_t;
typedef __attribute__((ext_vector_type(8))) _Float16 half8;
typedef __attribute__((ext_vector_type(4))) float floatx4;

// ---------------------------------------------------------------------------
// Pack B into MFMA-native fragment order + compute ||e||^2.
// Bp[ct][pk][lane][8]: ct = 16-code tile (64 tiles), pk = packed k-step
// (16 = seg0 hi + seg1 lo; phase 16..23 reuses pk 0..7 -> 1MB total),
// lane: col=lane&15 (code), k = (lane>>4)*8 + j.
__global__ __launch_bounds__(256)
void k_prep2(const float* __restrict__ emb, float* __restrict__ enorm,
             half_t* __restrict__ Bp) {
    __shared__ half_t hi[16 * 256];
    __shared__ half_t lo[16 * 256];
    __shared__ float  ssum[256];
    const int ct  = blockIdx.x;       // 16-code tile
    const int tid = threadIdx.x;
    const int c16 = tid >> 4;         // code within tile
    const int dp  = tid & 15;         // 16-dim part

    float ss = 0.f;
    #pragma unroll
    for (int i = 0; i < 4; ++i) {
        float4 v = *(const float4*)(emb + (size_t)(ct * 16 + c16) * DDIM + dp * 16 + i * 4);
        ss += v.x * v.x + v.y * v.y + v.z * v.z + v.w * v.w;
        #pragma unroll
        for (int q = 0; q < 4; ++q) {
            float f = (&v.x)[q];
            half_t h = (half_t)f;
            hi[c16 * 256 + dp * 16 + i * 4 + q] = h;
            lo[c16 * 256 + dp * 16 + i * 4 + q] = (half_t)(f - (float)h);
        }
    }
    ssum[tid] = ss;
    __syncthreads();
    if (tid < 16) {
        float s = 0.f;
        #pragma unroll
        for (int i = 0; i < 16; ++i) s += ssum[tid * 16 + i];
        enorm[ct * 16 + tid] = s;
    }

    // write phase: 16 packed steps x 64 lanes x 8 halfs
    #pragma unroll
    for (int i = 0; i < 4; ++i) {
        int f    = tid + i * 256;     // 0..1023
        int ks   = f >> 6;            // 0..15
        int lane = f & 63;
        int cc   = lane & 15;
        int seg  = ks >> 3;           // 0:hi 1:lo
        int ko   = (ks & 7) * 32 + (lane >> 4) * 8;
        const half_t* src = (seg == 1) ? lo : hi;
        half8 v = *(const half8*)(src + cc * 256 + ko);
        *(half8*)(Bp + ((size_t)(ct * 16 + ks) * 64 + lane) * 8) = v;
    }
}

// ---------------------------------------------------------------------------
// MFMA argmin. dist(r,c)=||e||^2-2 z.e; fp16 hi/lo K-concat (K'=768):
// phase c=0: z_hi.e_hi, c=1: z_hi.e_lo, c=2: z_lo.e_hi (B reuses pk 0..7).
// Block: 64 rows, 256 thr; As 64KB staged once; barrier-free K-loop.
// Wave w owns codes [w*256,(w+1)*256): 4 groups x (4m x 4n) 16x16x32 MFMA;
// depth-3 4-buffer rotating prefetch of PACKED coalesced 1KB B-frags.
// PLAIN __launch_bounds__(256): rounds 5 & 7 proved any min-waves hint makes
// the allocator spill the K-loop prefetch buffers to scratch (R7: VGPR 128,
// +150MB sym. FETCH/WRITE excess, 215us). LDS caps us at 2 blocks/CU anyway.
__global__ __launch_bounds__(256)
void k_argmin(const float* __restrict__ z, const half_t* __restrict__ Bp,
              const float* __restrict__ enorm, const float* __restrict__ embf,
              int* __restrict__ out_idx, float* __restrict__ out_idx_f,
              float* __restrict__ out_zq, float* __restrict__ lossp,
              int* __restrict__ counts_i) {
    __shared__ __align__(16) half_t As[RPB * 512];   // 64 KB

    const int tid  = threadIdx.x;
    const int w    = tid >> 6;
    const int lane = tid & 63;
    const int tx   = lane & 15;
    const int quad = lane >> 4;
    const int rbase = blockIdx.x * RPB;

    // ---- stage A: read z fp32, split hi/lo in-register, swizzled LDS store
    #pragma unroll
    for (int it = 0; it < 8; ++it) {
        int f   = tid + it * 256;
        int row = f >> 5;             // 0..63
        int g   = f & 31;
        const float* zp = z + (size_t)(rbase + row) * DDIM + g * 8;
        float4 v0 = *(const float4*)zp;
        float4 v1 = *(const float4*)(zp + 4);
        half8 hi, lo;
        hi[0] = (half_t)v0.x; lo[0] = (half_t)(v0.x - (float)hi[0]);
        hi[1] = (half_t)v0.y; lo[1] = (half_t)(v0.y - (float)hi[1]);
        hi[2] = (half_t)v0.z; lo[2] = (half_t)(v0.z - (float)hi[2]);
        hi[3] = (half_t)v0.w; lo[3] = (half_t)(v0.w - (float)hi[3]);
        hi[4] = (half_t)v1.x; lo[4] = (half_t)(v1.x - (float)hi[4]);
        hi[5] = (half_t)v1.y; lo[5] = (half_t)(v1.y - (float)hi[5]);
        hi[6] = (half_t)v1.z; lo[6] = (half_t)(v1.z - (float)hi[6]);
        hi[7] = (half_t)v1.w; lo[7] = (half_t)(v1.w - (float)hi[7]);
        int sw = row & 7;
        *(half8*)(&As[row * 512 + ((g ^ sw)) * 8])        = hi;  // k8 = g
        *(half8*)(&As[row * 512 + (((32 + g) ^ sw)) * 8]) = lo;  // k8 = 32+g
    }
    __syncthreads();                  // the ONLY main-loop barrier

    floatx4 zero4 = {0.f, 0.f, 0.f, 0.f};
    float bd[4][4];
    int   bi[4][4];
    #pragma unroll
    for (int mt = 0; mt < 4; ++mt)
        #pragma unroll
        for (int r = 0; r < 4; ++r) { bd[mt][r] = 3.402823466e38f; bi[mt][r] = 0; }

    for (int g4 = 0; g4 < 4; ++g4) {
        const int cb = w * 256 + g4 * 64;
        // wave's 4 tiles this group: global ct = w*16 + g4*4 + ns
        // Bp layout: ct stride 8192 halfs, pk stride 512, lane stride 8
        const half_t* Bg = Bp + (size_t)(w * 16 + g4 * 4) * 8192 + lane * 8;

        floatx4 acc[4][4];
        #pragma unroll
        for (int mt = 0; mt < 4; ++mt)
            #pragma unroll
            for (int ns = 0; ns < 4; ++ns) acc[mt][ns] = zero4;

        half8 B0[4], B1[4], B2[4], B3[4];
        // phase P -> packed index (phases 16..23 reuse 0..7, L2-warm)
        #define LOADB(P, BUF)                                                  \
            { const int pk_ = ((P) < 16) ? (P) : ((P) - 16);                   \
              _Pragma("unroll")                                                \
              for (int ns = 0; ns < 4; ++ns)                                   \
                  BUF[ns] = *(const half8*)(Bg + (size_t)(ns * 16 + pk_) * 512); }
        LOADB(0, B0);
        LOADB(1, B1);
        LOADB(2, B2);

        #pragma unroll
        for (int ks = 0; ks < 24; ++ks) {
            if (ks + 3 < 24) {                    // prefetch depth 3
                const int pb = (ks + 3) & 3;
                if      (pb == 0) { LOADB(ks + 3, B0); }
                else if (pb == 1) { LOADB(ks + 3, B1); }
                else if (pb == 2) { LOADB(ks + 3, B2); }
                else              { LOADB(ks + 3, B3); }
            }
            const int c   = ks >> 3;
            const int k8b = (c == 2 ? 32 : 0) + (ks & 7) * 4;
            half8 a[4];
            #pragma unroll
            for (int mt = 0; mt < 4; ++mt) {
                int row = mt * 16 + tx;
                a[mt] = *(half8*)(&As[row * 512 + ((k8b + quad) ^ (row & 7)) * 8]);
            }
            #pragma unroll
            for (int mt = 0; mt < 4; ++mt)
                #pragma unroll
                for (int ns = 0; ns < 4; ++ns) {
                    const int cbuf = ks & 3;
                    const half8& bb = (cbuf == 0) ? B0[ns] :
                                      (cbuf == 1) ? B1[ns] :
                                      (cbuf == 2) ? B2[ns] : B3[ns];
                    acc[mt][ns] = __builtin_amdgcn_mfma_f32_16x16x32_f16(a[mt], bb, acc[mt][ns], 0, 0, 0);
                }
        }
        #undef LOADB

        // fold group into running argmin (codes ascending; strict <, min-index)
        #pragma unroll
        for (int ns = 0; ns < 4; ++ns) {
            float en = enorm[cb + ns * 16 + tx];
            int   cc = cb + ns * 16 + tx;
            #pragma unroll
            for (int mt = 0; mt < 4; ++mt)
                #pragma unroll
                for (int r = 0; r < 4; ++r) {
                    float d = fmaf(-2.f, acc[mt][ns][r], en);
                    if (d < bd[mt][r]) { bd[mt][r] = d; bi[mt][r] = cc; }
                }
        }
    }

    // reduce across 16 tx lanes (same row, different codes); ties -> min index
    #pragma unroll
    for (int mt = 0; mt < 4; ++mt)
        #pragma unroll
        for (int r = 0; r < 4; ++r) {
            float d = bd[mt][r];
            int   b = bi[mt][r];
            #pragma unroll
            for (int off = 8; off > 0; off >>= 1) {
                float od = __shfl_xor(d, off);
                int   ob = __shfl_xor(b, off);
                if (od < d || (od == d && ob < b)) { d = od; b = ob; }
            }
            bd[mt][r] = d; bi[mt][r] = b;
        }

    // cross-wave reduce via LDS (reuse As)
    __syncthreads();
    float* sd   = (float*)As;          // [64 rows][4 waves]
    int*   si   = ((int*)As) + 256;
    int*   sidx = ((int*)As) + 512;    // final idx per row
    if (tx == 0) {
        #pragma unroll
        for (int mt = 0; mt < 4; ++mt)
            #pragma unroll
            for (int r = 0; r < 4; ++r) {
                int row = mt * 16 + quad * 4 + r;   // C-layout: row = quad*4+reg
                sd[row * 4 + w] = bd[mt][r];
                si[row * 4 + w] = bi[mt][r];
            }
    }
    __syncthreads();
    if (tid < RPB) {
        int row = tid;
        float d = sd[row * 4];
        int   b = si[row * 4];
        #pragma unroll
        for (int ww = 1; ww < 4; ++ww) {
            float od = sd[row * 4 + ww];
            int   ob = si[row * 4 + ww];
            if (od < d || (od == d && ob < b)) { d = od; b = ob; }
        }
        sidx[row] = b;
        out_idx[rbase + row]   = b;
        out_idx_f[rbase + row] = (float)b;
        atomicAdd(&counts_i[b], 1);
    }
    __syncthreads();

    // ---- fused z_q epilogue: z_q_st write + commitment-loss partial
    float l = 0.f;
    #pragma unroll
    for (int u = 0; u < 16; ++u) {
        int gi  = tid + u * 256;       // 0..4095 float4s = 64 rows x 64
        int row = gi >> 6;
        int c4  = gi & 63;
        int k   = sidx[row];           // wave-uniform
        float4 zv = *(const float4*)(z    + (size_t)(rbase + row) * DDIM + c4 * 4);
        float4 ev = *(const float4*)(embf + (size_t)k * DDIM + c4 * 4);
        float dx = ev.x - zv.x, dy = ev.y - zv.y, dz = ev.z - zv.z, dw = ev.w - zv.w;
        float4 o = { zv.x + dx, zv.y + dy, zv.z + dz, zv.w + dw };  // z + (z_q - z)
        *(float4*)(out_zq + (size_t)(rbase + row) * DDIM + c4 * 4) = o;
        l += dx * dx + dy * dy + dz * dz + dw * dw;
    }
    #pragma unroll
    for (int off = 32; off > 0; off >>= 1) l += __shfl_down(l, off);
    __shared__ float ls[4];
    if (lane == 0) ls[w] = l;
    __syncthreads();
    if (tid == 0) lossp[blockIdx.x] = ls[0] + ls[1] + ls[2] + ls[3];
}

// ---------------------------------------------------------------------------
// Single block: prefix-sum counts -> cursors; ncs/n/loss finalization.
__global__ __launch_bounds__(256)
void k_scan(const float* __restrict__ cs_in, const int* __restrict__ counts_i,
            const float* __restrict__ lossp, float* __restrict__ out_ncs,
            int* __restrict__ cursors,
            float* __restrict__ n_out, float* __restrict__ loss_out) {
    const int tid = threadIdx.x;
    __shared__ int ps[256];
    int c[4]; int pt = 0;
    #pragma unroll
    for (int i = 0; i < 4; ++i) { c[i] = counts_i[tid * 4 + i]; pt += c[i]; }
    ps[tid] = pt;
    __syncthreads();
    for (int s = 1; s < 256; s <<= 1) {
        int v = (tid >= s) ? ps[tid - s] : 0;
        __syncthreads();
        ps[tid] += v;
        __syncthreads();
    }
    int o = ps[tid] - pt;              // exclusive base for this thread's 4 bins
    float v = 0.f;
    #pragma unroll
    for (int i = 0; i < 4; ++i) {
        cursors[tid * 4 + i] = o;
        o += c[i];
        float nc = cs_in[tid * 4 + i] * 0.99f + 0.01f * (float)c[i];
        out_ncs[tid * 4 + i] = nc;
        v += nc;
    }
    float l = 0.f;
    for (int i = tid; i < NBLK; i += 256) l += lossp[i];
    #pragma unroll
    for (int off = 32; off > 0; off >>= 1) {
        v += __shfl_down(v, off);
        l += __shfl_down(l, off);
    }
    __shared__ float sv[4], sl[4];
    if ((tid & 63) == 0) { sv[tid >> 6] = v; sl[tid >> 6] = l; }
    __syncthreads();
    if (tid == 0) {
        n_out[0]    = sv[0] + sv[1] + sv[2] + sv[3];
        loss_out[0] = 0.25f * ((sl[0] + sl[1] + sl[2] + sl[3]) / 8388608.0f);
    }
}

// ---------------------------------------------------------------------------
// Scatter row ids into per-code contiguous lists (counting sort, phase 2).
__global__ __launch_bounds__(256)
void k_rank(const int* __restrict__ idx, int* __restrict__ cursors,
            int* __restrict__ rows_sorted) {
    int r = blockIdx.x * 256 + threadIdx.x;
    int k = idx[r];
    int pos = atomicAdd(&cursors[k], 1);
    rows_sorted[pos] = r;
}

// ---------------------------------------------------------------------------
// Skew-proof segment-sum: each wave owns exactly 64 sorted positions,
// accumulates equal-code runs in registers, flushes runs via fp32 atomics.
__global__ __launch_bounds__(128)
void k_esum2(const float* __restrict__ z, const int* __restrict__ rows_sorted,
             const int* __restrict__ idx, float* __restrict__ esum) {
    const int tid  = threadIdx.x;
    const int w    = tid >> 6;
    const int lane = tid & 63;
    const int base = (blockIdx.x * 2 + w) * 64;   // 256 blocks x 2 waves

    int r = rows_sorted[base + lane];
    int c = idx[r];
    float4 acc = {0.f, 0.f, 0.f, 0.f};
    #pragma unroll 8
    for (int j = 0; j < 64; ++j) {
        int rj = __shfl(r, j);
        int cj = __shfl(c, j);
        float4 zv = *(const float4*)(z + (size_t)rj * DDIM + lane * 4);
        acc.x += zv.x; acc.y += zv.y; acc.z += zv.z; acc.w += zv.w;
        int cn = (j < 63) ? __shfl(c, j + 1) : -1;
        if (cn != cj) {                // wave-uniform branch
            float* p = esum + (size_t)cj * DDIM + lane * 4;
            atomicAdd(p + 0, acc.x);
            atomicAdd(p + 1, acc.y);
            atomicAdd(p + 2, acc.z);
            atomicAdd(p + 3, acc.w);
            acc.x = 0.f; acc.y = 0.f; acc.z = 0.f; acc.w = 0.f;
        }
    }
}

// ---------------------------------------------------------------------------
__global__ __launch_bounds__(256)
void k_embed(const float* __restrict__ ea, const float* __restrict__ esum,
             const float* __restrict__ ncs, const float* __restrict__ n_ws,
             float* __restrict__ out_nea, float* __restrict__ out_nemb) {
    int k = blockIdx.x;
    int d = threadIdx.x;
    size_t off = (size_t)k * DDIM + d;
    float nea = ea[off] * 0.99f + 0.01f * esum[off];
    out_nea[off] = nea;
    float cs = (ncs[k] + 1e-6f) / (n_ws[0] + 0.001024f);   // (ncs+eps)/(n+K*eps)
    out_nemb[off] = nea / cs;
}

// ---------------------------------------------------------------------------
extern "C" void kernel_launch(void* const* d_in, const int* in_sizes, int n_in,
                              void* d_out, int out_size, void* d_ws, size_t ws_size,
                              hipStream_t stream) {
    const float* z   = (const float*)d_in[0];
    const float* emb = (const float*)d_in[1];
    const float* cs  = (const float*)d_in[2];
    const float* ea  = (const float*)d_in[3];
    float* out = (float*)d_out;
    float* ws  = (float*)d_ws;

    float* esum    = ws + W_ESUM;
    int*   cnts    = (int*)(ws + W_CNT);
    float* enorm   = ws + W_ENORM;
    float* lossp   = ws + W_LOSSP;
    int*   curs    = (int*)(ws + W_CUR);
    float* wn      = ws + W_N;
    int*   widx    = (int*)(ws + W_IDX);
    int*   rsorted = (int*)(ws + W_SORT);

    // packed-B fp16 scratch in dead O_NEA output region (16B-aligned;
    // k_embed, the only writer of that region, runs last). 1MB.
    half_t* Bp = (half_t*)(out + O_NEA + 3);   // 524288 halfs

    hipMemsetAsync(ws, 0, (size_t)(262144 + 1024) * sizeof(float), stream);
    k_prep2  <<<64, 256, 0, stream>>>(emb, enorm, Bp);
    k_argmin <<<NBLK, 256, 0, stream>>>(z, Bp, enorm, emb,
                                        widx, out + O_IDX, out + O_ZQ, lossp, cnts);
    k_scan   <<<1, 256, 0, stream>>>(cs, cnts, lossp, out + O_NCS, curs,
                                     wn, out + O_LOSS);
    k_rank   <<<N_ROWS / 256, 256, 0, stream>>>(widx, curs, rsorted);
    k_esum2  <<<256, 128, 0, stream>>>(z, rsorted, widx, esum);
    k_embed  <<<KCODES, 256, 0, stream>>>(ea, esum, out + O_NCS, wn,
                                          out + O_NEA, out + O_NEMB);
}